// Round 11
// baseline (111.597 us; speedup 1.0000x reference)
//
#include <hip/hip_runtime.h>
#include <hip/hip_bf16.h>
#include <stdint.h>

#define Bn 2
#define Np 50000
#define Cc 81
#define CM1 80
#define KSEL 2048
#define NDET 100
#define NBUCK 2048
#define BUCK_BASE 0x3D000000u
#define BUCK_SHIFT 15
#define BUCK_MAX 1280   // bucket of score 1.0 (softmax max) — nothing above
#define SELCAP 4096
#define IMG_W 1333.0f
#define IMG_H 800.0f
#define SCORE_TH 0.05f
#define MIN_SZ 0.01f
#define NMS_TH 0.5f
#define LBLOFF 1401.0f
#define BBOX_CLIP_F 4.135166556742356f
#define CHUNK 16
#define QCAP 320       // >= 16 proposals * 19 max emits (sum(softmax)=1)
#define BLKX 782       // ceil(Np / (4*CHUNK))
#define WPI  (BLKX*4)  // wave segments per image
#define BATCH 512      // tail NMS window

typedef unsigned long long u64;
typedef unsigned int u32;

// Torchvision BoxCoder.decode + clip, non-contracted fp32 to match reference.
__device__ __forceinline__ void decode_box(int row, int c,
    const float* __restrict__ reg, const float* __restrict__ props,
    float& x1, float& y1, float& x2, float& y2) {
  const float4 pr = *reinterpret_cast<const float4*>(props + (size_t)row * 4);
  float w = __fsub_rn(pr.z, pr.x), h = __fsub_rn(pr.w, pr.y);
  float cx = __fadd_rn(pr.x, 0.5f * w), cy = __fadd_rn(pr.y, 0.5f * h);
  const float4 rel = *reinterpret_cast<const float4*>(reg + ((size_t)row * Cc + c) * 4);
  float dx = __fdiv_rn(rel.x, 10.f), dy = __fdiv_rn(rel.y, 10.f);
  float dw = fminf(__fdiv_rn(rel.z, 5.f), BBOX_CLIP_F);
  float dh = fminf(__fdiv_rn(rel.w, 5.f), BBOX_CLIP_F);
  float pcx = __fadd_rn(__fmul_rn(dx, w), cx);
  float pcy = __fadd_rn(__fmul_rn(dy, h), cy);
  float pw = __fmul_rn(expf(dw), w);
  float ph = __fmul_rn(expf(dh), h);
  x1 = fminf(fmaxf(__fsub_rn(pcx, 0.5f * pw), 0.f), IMG_W);
  y1 = fminf(fmaxf(__fsub_rn(pcy, 0.5f * ph), 0.f), IMG_H);
  x2 = fminf(fmaxf(__fadd_rn(pcx, 0.5f * pw), 0.f), IMG_W);
  y2 = fminf(fmaxf(__fadd_rn(pcy, 0.5f * ph), 0.f), IMG_H);
}

// Quad-split softmax over one wave's 16-proposal LDS slab. Reduce orders
// bit-identical to rounds 3..10 (all matched the reference exactly).
#define SOFTMAX_PROLOG(S)                                            \
  const int p = lane >> 2, qd = lane & 3;                            \
  const int base = p * Cc + qd * 21;                                 \
  const int cnt_k = (qd == 3) ? 18 : 21;                             \
  float ev[21];                                                      \
  _Pragma("unroll")                                                  \
  for (int k = 0; k < 21; ++k)                                       \
    ev[k] = (k < cnt_k) ? (S)[base + k] : -3.4e38f;                  \
  float m = ev[0];                                                   \
  _Pragma("unroll")                                                  \
  for (int k = 1; k < 21; ++k) m = fmaxf(m, ev[k]);                  \
  m = fmaxf(m, __shfl_xor(m, 1, 64));                                \
  m = fmaxf(m, __shfl_xor(m, 2, 64));                                \
  float s = 0.f;                                                     \
  _Pragma("unroll")                                                  \
  for (int k = 0; k < 21; ++k) {                                     \
    ev[k] = (k < cnt_k) ? expf(ev[k] - m) : 0.f;                     \
    s += ev[k];                                                      \
  }                                                                  \
  s += __shfl_xor(s, 1, 64);                                         \
  s += __shfl_xor(s, 2, 64);                                         \
  const float thr = SCORE_TH * s;

// Stage 16 proposals x 81 logits (324 float4, coalesced) into the wave slab.
#define STAGE_LOGITS(S, src)                                         \
  _Pragma("unroll")                                                  \
  for (int i = 0; i < 6; ++i) {                                      \
    const int f4 = i * 64 + lane;                                    \
    if (f4 < (CHUNK * Cc) / 4) {                                     \
      const float4 v = *reinterpret_cast<const float4*>((src) + (size_t)f4 * 4); \
      *reinterpret_cast<float4*>(&(S)[f4 * 4]) = v;                  \
    }                                                                \
  }

// Pass A: softmax -> per-lane emit mask -> ONE wave prefix scan -> unrolled
// compacted writes to the private per-wave segment + LDS hist ->
// fire-and-forget global hist flush. (Replaces 21 serial ballot chains.)
__global__ __launch_bounds__(256, 4) void passA_kernel(
    const float* __restrict__ logits, u64* __restrict__ wseg,
    u32* __restrict__ wcnt, u32* __restrict__ ghist)
{
  __shared__ __align__(16) float stg[4][CHUNK * Cc];   // 20736 B
  __shared__ u32 hist[NBUCK];                          // 8192 B
  const int b = blockIdx.y;
  const int tid = threadIdx.x;
  const int wave = tid >> 6, lane = tid & 63;
  for (int i = tid; i < NBUCK; i += 256) hist[i] = 0;
  __syncthreads();

  const int wslot = (blockIdx.x << 2) + wave;
  const int n0 = wslot * CHUNK;
  u64* seg = wseg + (size_t)(b * WPI + wslot) * QCAP;
  u32 wtot = 0;
  if (n0 < Np) {
    float* S = stg[wave];
    STAGE_LOGITS(S, logits + ((size_t)b * Np + n0) * Cc)
    SOFTMAX_PROLOG(S)
    const int n_ = n0 + p;
    u32 emask = 0;
    #pragma unroll
    for (int k = 0; k < 21; ++k) {
      const int c = qd * 21 + k;
      if (c > 0 && ev[k] > thr) emask |= (1u << k);
    }
    const u32 mycnt = __popc(emask);
    u32 inc = mycnt;
    #pragma unroll
    for (int o = 1; o < 64; o <<= 1) {
      const u32 v = (u32)__shfl_up((int)inc, o, 64);
      if (lane >= o) inc += v;
    }
    u32 pos = inc - mycnt;
    wtot = (u32)__shfl((int)inc, 63, 64);
    #pragma unroll
    for (int k = 0; k < 21; ++k) {
      if (emask & (1u << k)) {
        const int c = qd * 21 + k;
        const u32 sb = __float_as_uint(__fdiv_rn(ev[k], s));
        const u32 idx = (u32)(n_ * CM1 + (c - 1));
        seg[pos++] = ((u64)sb << 32) | (u32)(~idx);
        u32 bk = (sb - BUCK_BASE) >> BUCK_SHIFT;
        if (bk > (u32)(NBUCK - 1)) bk = NBUCK - 1;
        atomicAdd(&hist[bk], 1u);
      }
    }
  }
  if (lane == 0) wcnt[b * WPI + wslot] = wtot;
  __syncthreads();
  for (int i = tid; i < NBUCK; i += 256) {
    const u32 v = hist[i];
    if (v) atomicAdd(&ghist[b * NBUCK + i], v);   // fire-and-forget
  }
}

// Per image: T = largest bucket with inclusive suffix >= KSEL (0 if total
// < KSEL); exclusive suffix offsets; total selected (clamped to SELCAP).
__global__ void thresh_kernel(const u32* __restrict__ ghist, u32* __restrict__ gT,
                              u32* __restrict__ gTot, u32* __restrict__ boffs) {
  const int b = blockIdx.x;
  const int lane = threadIdx.x;  // 64 threads
  const u32* h = ghist + b * NBUCK;
  u32* bo = boffs + b * NBUCK;
  const int SEG = NBUCK / 64;
  u32 segsum = 0;
  for (int t = 0; t < SEG; ++t) segsum += h[lane * SEG + t];
  u32 suf = segsum;
  #pragma unroll
  for (int o = 1; o < 64; o <<= 1) {
    const u32 v = (u32)__shfl_down((int)suf, o, 64);
    if (lane + o < 64) suf += v;
  }
  u32 acc = suf - segsum;   // count in buckets strictly above this segment
  int myT = -1; u32 totv = 0;
  for (int t = SEG - 1; t >= 0; --t) {
    const int bk = lane * SEG + t;
    bo[bk] = acc;
    acc += h[bk];
    if (myT < 0 && acc >= (u32)KSEL) { myT = bk; totv = acc; }
  }
  int Tg = myT;
  #pragma unroll
  for (int o = 32; o; o >>= 1) Tg = max(Tg, __shfl_xor(Tg, o, 64));
  if (Tg < 0) {
    if (lane == 0) { gT[b] = 0u; gTot[b] = (acc < (u32)SELCAP) ? acc : (u32)SELCAP; }
  } else if (myT == Tg) {
    gT[b] = (u32)Tg;
    gTot[b] = (totv < (u32)SELCAP) ? totv : (u32)SELCAP;
  }
}

// Scatter: wave-per-segment. Keys with bucket >= T (~2100/image) are
// decoded + minsize-filtered, then placed via per-bucket fill atomics.
__global__ __launch_bounds__(256) void scatter_kernel(
    const u64* __restrict__ wseg, const u32* __restrict__ wcnt,
    const u32* __restrict__ gT, const u32* __restrict__ boffs,
    u32* __restrict__ bfill, u64* __restrict__ skeys,
    const float* __restrict__ reg, const float* __restrict__ props)
{
  const int b = blockIdx.y;
  const u32 T = gT[b];
  const int wave = threadIdx.x >> 6, lane = threadIdx.x & 63;
  const u32 sgi = blockIdx.x * 4 + wave;
  if (sgi >= (u32)WPI) return;
  const u32 cnt = wcnt[b * WPI + sgi];
  const u64* seg = wseg + (size_t)(b * WPI + sgi) * QCAP;
  for (u32 i = lane; i < cnt; i += 64) {
    const u64 key = seg[i];
    const u32 sb = (u32)(key >> 32);
    u32 bk = (sb - BUCK_BASE) >> BUCK_SHIFT;
    if (bk > (u32)(NBUCK - 1)) bk = NBUCK - 1;
    if (bk >= T) {
      const u32 idx = ~(u32)key;
      const int pn = (int)(idx / CM1);
      const int c = (int)(idx % CM1) + 1;
      float x1, y1, x2, y2;
      decode_box(b * Np + pn, c, reg, props, x1, y1, x2, y2);
      if (__fsub_rn(x2, x1) >= MIN_SZ && __fsub_rn(y2, y1) >= MIN_SZ) {
        const u32 pos = boffs[b * NBUCK + bk] + atomicAdd(&bfill[b * NBUCK + bk], 1u);
        if (pos < (u32)SELCAP) skeys[(size_t)b * SELCAP + pos] = key;
      }
    }
  }
}

// Lazy tail: stage the bucket-descending key span in LDS; per 512-key
// window: rank-sort only newly-entered bucket runs (wave-per-run,
// broadcast reads, data-dependent trip), decode window to LDS SoA, run
// the wave-0 greedy NMS (early-exit at 100). Walk starts at BUCK_MAX and
// usually terminates after the first window. One block per image.
__global__ __launch_bounds__(256) void tail_kernel(
    const u64* __restrict__ skeys, const u32* __restrict__ gT,
    const u32* __restrict__ gTot, const u32* __restrict__ boffs,
    const float* __restrict__ reg, const float* __restrict__ props,
    float* __restrict__ out)
{
  __shared__ u64 skl[SELCAP];                                  // 32 KB
  __shared__ u32 sbo[NBUCK];                                   // 8 KB
  __shared__ float sx1[BATCH], sy1[BATCH], sx2[BATCH], sy2[BATCH];
  __shared__ float ssc[BATCH], slb[BATCH];                     // 12 KB
  __shared__ u32 lsrc[BATCH], lwid[BATCH];                     // 4 KB
  __shared__ float kox1[NDET], koy1[NDET], kox2[NDET], koy2[NDET], kar[NDET];
  __shared__ float kx1[NDET], ky1[NDET], kx2[NDET], ky2[NDET], ksc[NDET], klb[NDET];
  __shared__ u32 sh_ns, sh_wend, sh_kc; __shared__ int sh_bk;
  const int b = blockIdx.x;
  const int tid = threadIdx.x;
  const int wave = tid >> 6, lane = tid & 63;
  const u32 T = gT[b];
  const u32 gTotb = gTot[b];
  const u32 TOT = (gTotb < (u32)KSEL) ? gTotb : (u32)KSEL;
  for (int i = tid; i < SELCAP; i += 256) skl[i] = skeys[(size_t)b * SELCAP + i];
  for (int i = tid; i < NBUCK; i += 256) sbo[i] = boffs[b * NBUCK + i];
  if (tid == 0) { sh_kc = 0; sh_bk = BUCK_MAX; }
  __syncthreads();

  u32 wbeg = 0;
  int kc = 0;
  while (kc < NDET && wbeg < TOT) {
    // --- builder (thread 0): window [wbeg, wend) + list of new runs to sort
    if (tid == 0) {
      const u32 wend_t = (wbeg + (u32)BATCH < TOT) ? (wbeg + (u32)BATCH) : TOT;
      int bk = sh_bk;
      u32 ns = 0;
      while (bk >= (int)T && sbo[bk] < wend_t && ns < (u32)BATCH) {
        const u32 st = sbo[bk];
        u32 nxt = (bk > 0) ? sbo[bk - 1] : gTotb;
        if (nxt > gTotb) nxt = gTotb;
        if (nxt > st) { lsrc[ns] = st; lwid[ns] = nxt - st; ++ns; }
        --bk;
      }
      sh_ns = ns; sh_wend = wend_t; sh_bk = bk;
    }
    __syncthreads();
    const u32 ns = sh_ns;
    const u32 wend = sh_wend;
    // --- sort newly-entered runs in place (wave per run; zeros sink last)
    for (u32 e = wave; e < ns; e += 4) {
      const u32 st = lsrc[e], W = lwid[e];
      if (W < 2) continue;
      if (W <= 128u) {
        const u64 k0 = (lane < (int)W) ? skl[st + lane] : 0ull;
        const u64 k1 = (64 + lane < (int)W) ? skl[st + 64 + lane] : 0ull;
        u32 r0 = 0, r1 = 0;
        for (u32 q = 0; q < W; ++q) {
          const u64 kq = skl[st + q];   // broadcast read
          r0 += (kq > k0); r1 += (kq > k1);
        }
        if (lane < (int)W) skl[st + r0] = k0;          // wave-lockstep:
        if (64 + lane < (int)W) skl[st + r1] = k1;     // reads precede writes
      } else if (W <= 512u) {
        u64 kk[8]; u32 rr[8];
        #pragma unroll
        for (int j = 0; j < 8; ++j) {
          kk[j] = ((u32)(j * 64) + lane < W) ? skl[st + j * 64 + lane] : 0ull;
          rr[j] = 0;
        }
        for (u32 q = 0; q < W; ++q) {
          const u64 kq = skl[st + q];
          #pragma unroll
          for (int j = 0; j < 8; ++j) rr[j] += (kq > kk[j]);
        }
        #pragma unroll
        for (int j = 0; j < 8; ++j)
          if ((u32)(j * 64) + lane < W) skl[st + rr[j]] = kk[j];
      } else {
        // Cold path (not expected): in-LDS odd-even transposition.
        for (u32 ph = 0; ph < W; ++ph)
          for (u32 q = lane; 2 * q + (ph & 1) + 1 < W; q += 64) {
            const u32 i0 = st + 2 * q + (ph & 1);
            const u64 a = skl[i0], c2 = skl[i0 + 1];
            if (a < c2) { skl[i0] = c2; skl[i0 + 1] = a; }
          }
      }
    }
    __syncthreads();
    // --- decode window to SoA (256 threads; ~512 scattered reg lines)
    const u32 bn = wend - wbeg;
    for (u32 i = tid; i < bn; i += 256) {
      const u64 key = skl[wbeg + i];
      float x1 = 0, y1 = 0, x2 = 0, y2 = 0, sc = 0, lb = 0;
      if (key) {
        const u32 sb = (u32)(key >> 32);
        const u32 idx = ~(u32)key;
        const int n_ = (int)(idx / CM1);
        const int c = (int)(idx % CM1) + 1;
        sc = __uint_as_float(sb);
        decode_box(b * Np + n_, c, reg, props, x1, y1, x2, y2);
        lb = (float)c;
      }
      sx1[i] = x1; sy1[i] = y1; sx2[i] = x2; sy2[i] = y2; ssc[i] = sc; slb[i] = lb;
    }
    __syncthreads();
    // --- wave 0: greedy NMS over the window (r10's proven loop, LDS src)
    if (wave == 0) {
      int kcl = kc;
      for (u32 base = 0; base < bn && kcl < NDET; base += 64) {
        const u32 pos = base + lane;
        const bool inb = pos < bn;
        float x1 = 0, y1 = 0, x2 = 0, y2 = 0, sc = 0, lb = 0;
        if (inb) {
          x1 = sx1[pos]; y1 = sy1[pos]; x2 = sx2[pos]; y2 = sy2[pos];
          sc = ssc[pos]; lb = slb[pos];
        }
        const float offv = __fmul_rn(lb, LBLOFF);
        const float ox1 = __fadd_rn(x1, offv), oy1 = __fadd_rn(y1, offv);
        const float ox2 = __fadd_rn(x2, offv), oy2 = __fadd_rn(y2, offv);
        const float ar = __fmul_rn(__fsub_rn(ox2, ox1), __fsub_rn(oy2, oy1));
        const bool valid = inb && (sc > 0.f);
        bool sup = false;
        for (int k = 0; k < kcl; ++k) {
          const float ltx = fmaxf(ox1, kox1[k]), lty = fmaxf(oy1, koy1[k]);
          const float rbx = fminf(ox2, kox2[k]), rby = fminf(oy2, koy2[k]);
          const float wx = fmaxf(__fsub_rn(rbx, ltx), 0.f);
          const float wy = fmaxf(__fsub_rn(rby, lty), 0.f);
          const float inter = __fmul_rn(wx, wy);
          const float denom = __fadd_rn(__fsub_rn(__fadd_rn(ar, kar[k]), inter), 1e-9f);
          if (__fdiv_rn(inter, denom) > NMS_TH) sup = true;
        }
        u64 rem = __ballot(sup) | ~__ballot(valid);
        u64 todo = ~rem;
        while (todo && kcl < NDET) {
          const int jb = (int)__builtin_ctzll(todo);
          const float bx1 = __shfl(ox1, jb, 64), by1 = __shfl(oy1, jb, 64);
          const float bx2 = __shfl(ox2, jb, 64), by2 = __shfl(oy2, jb, 64);
          const float ba  = __shfl(ar, jb, 64);
          if (lane == jb) {
            kox1[kcl] = ox1; koy1[kcl] = oy1; kox2[kcl] = ox2; koy2[kcl] = oy2; kar[kcl] = ar;
            kx1[kcl] = x1; ky1[kcl] = y1; kx2[kcl] = x2; ky2[kcl] = y2; ksc[kcl] = sc; klb[kcl] = lb;
          }
          const float ltx = fmaxf(ox1, bx1), lty = fmaxf(oy1, by1);
          const float rbx = fminf(ox2, bx2), rby = fminf(oy2, by2);
          const float wx = fmaxf(__fsub_rn(rbx, ltx), 0.f);
          const float wy = fmaxf(__fsub_rn(rby, lty), 0.f);
          const float inter = __fmul_rn(wx, wy);
          const float denom = __fadd_rn(__fsub_rn(__fadd_rn(ar, ba), inter), 1e-9f);
          const u64 w = __ballot(__fdiv_rn(inter, denom) > NMS_TH);
          rem |= w;
          todo &= ~rem;
          todo &= ~(1ull << jb);
          ++kcl;
        }
      }
      if (lane == 0) sh_kc = (u32)kcl;
    }
    __syncthreads();
    kc = (int)sh_kc;
    wbeg = wend;
  }

  // Output: first min(kc,100) kept, padded with zeros / label -1.
  __syncthreads();
  const int kcl = (kc < NDET) ? kc : NDET;
  if (tid < NDET) {
    float bx1 = 0, by1 = 0, bx2 = 0, by2 = 0, sc = 0, lb = -1.f;
    if (tid < kcl) {
      bx1 = kx1[tid]; by1 = ky1[tid]; bx2 = kx2[tid]; by2 = ky2[tid];
      sc = ksc[tid]; lb = klb[tid];
    }
    float* ob = out + (size_t)b * NDET * 4;
    ob[tid * 4 + 0] = bx1; ob[tid * 4 + 1] = by1;
    ob[tid * 4 + 2] = bx2; ob[tid * 4 + 3] = by2;
    out[Bn * NDET * 4 + b * NDET + tid] = sc;
    out[Bn * NDET * 4 + Bn * NDET + b * NDET + tid] = lb;
  }
}

extern "C" void kernel_launch(void* const* d_in, const int* in_sizes, int n_in,
                              void* d_out, int out_size, void* d_ws, size_t ws_size,
                              hipStream_t stream) {
  const float* logits = (const float*)d_in[0];
  const float* reg    = (const float*)d_in[1];
  const float* props  = (const float*)d_in[2];
  float* out = (float*)d_out;
  char* ws = (char*)d_ws;

  // Layout: [header | ghist | bfill | skeys] <- memset 0 each call (96 KB)
  //         [boffs | wcnt | wseg]            <- count/overwrite-guarded
  u32* gT   = (u32*)ws;                        // 2 u32
  u32* gTot = (u32*)(ws + 16);                 // 2 u32
  size_t off = 64;
  u32* ghist = (u32*)(ws + off); off += (size_t)Bn * NBUCK * 4;    // 16 KB
  u32* bfill = (u32*)(ws + off); off += (size_t)Bn * NBUCK * 4;    // 16 KB
  u64* skeys = (u64*)(ws + off); off += (size_t)Bn * SELCAP * 8;   // 64 KB
  const size_t memset_bytes = off;
  u32* boffs = (u32*)(ws + off); off += (size_t)Bn * NBUCK * 4;    // 16 KB
  u32* wcnt  = (u32*)(ws + off); off += (size_t)Bn * WPI * 4;      // 25 KB
  off = (off + 255) & ~(size_t)255;
  u64* wseg  = (u64*)(ws + off); off += (size_t)Bn * WPI * QCAP * 8;   // 16 MB
  (void)ws_size;

  hipMemsetAsync(d_ws, 0, memset_bytes, stream);
  passA_kernel<<<dim3(BLKX, Bn), 256, 0, stream>>>(logits, wseg, wcnt, ghist);
  thresh_kernel<<<dim3(Bn), 64, 0, stream>>>(ghist, gT, gTot, boffs);
  scatter_kernel<<<dim3((WPI + 3) / 4, Bn), 256, 0, stream>>>(wseg, wcnt, gT, boffs, bfill, skeys, reg, props);
  tail_kernel<<<dim3(Bn), 256, 0, stream>>>(skeys, gT, gTot, boffs, reg, props, out);
}

// Round 12
// 78.130 us; speedup vs baseline: 1.4284x; 1.4284x over previous
//
#include <hip/hip_runtime.h>
#include <hip/hip_bf16.h>
#include <stdint.h>

#define Bn 2
#define Np 50000
#define Cc 81
#define CM1 80
#define KSEL 2048
#define NDET 100
#define NBUCK 2048
#define BUCK_BASE 0x3D000000u
#define BUCK_SHIFT 15
#define SELCAP 4096
#define IMG_W 1333.0f
#define IMG_H 800.0f
#define SCORE_TH 0.05f
#define MIN_SZ 0.01f
#define NMS_TH 0.5f
#define LBLOFF 1401.0f
#define BBOX_CLIP_F 4.135166556742356f
#define CHUNK 32       // proposals per wave (2 rounds of 16)
#define QCAP 320       // >= 16 proposals * 19 max emits per round
#define BLKX 391       // ceil(Np / (4*CHUNK))
#define WPI  (BLKX*4)  // wave segments per image
#define RS_WPB 4       // runsort waves per block

typedef unsigned long long u64;
typedef unsigned int u32;

__device__ __forceinline__ u64 shfl64(u64 v, int src) {
  int lo = __shfl((int)(u32)v, src, 64);
  int hi = __shfl((int)(u32)(v >> 32), src, 64);
  return ((u64)(u32)hi << 32) | (u32)lo;
}

// Torchvision BoxCoder.decode + clip, non-contracted fp32 to match reference.
__device__ __forceinline__ void decode_box(int row, int c,
    const float* __restrict__ reg, const float* __restrict__ props,
    float& x1, float& y1, float& x2, float& y2) {
  const float4 pr = *reinterpret_cast<const float4*>(props + (size_t)row * 4);
  float w = __fsub_rn(pr.z, pr.x), h = __fsub_rn(pr.w, pr.y);
  float cx = __fadd_rn(pr.x, 0.5f * w), cy = __fadd_rn(pr.y, 0.5f * h);
  const float4 rel = *reinterpret_cast<const float4*>(reg + ((size_t)row * Cc + c) * 4);
  float dx = __fdiv_rn(rel.x, 10.f), dy = __fdiv_rn(rel.y, 10.f);
  float dw = fminf(__fdiv_rn(rel.z, 5.f), BBOX_CLIP_F);
  float dh = fminf(__fdiv_rn(rel.w, 5.f), BBOX_CLIP_F);
  float pcx = __fadd_rn(__fmul_rn(dx, w), cx);
  float pcy = __fadd_rn(__fmul_rn(dy, h), cy);
  float pw = __fmul_rn(expf(dw), w);
  float ph = __fmul_rn(expf(dh), h);
  x1 = fminf(fmaxf(__fsub_rn(pcx, 0.5f * pw), 0.f), IMG_W);
  y1 = fminf(fmaxf(__fsub_rn(pcy, 0.5f * ph), 0.f), IMG_H);
  x2 = fminf(fmaxf(__fadd_rn(pcx, 0.5f * pw), 0.f), IMG_W);
  y2 = fminf(fmaxf(__fadd_rn(pcy, 0.5f * ph), 0.f), IMG_H);
}

// Batched drain (r9-proven): 64 lanes decode+minsize-filter queued keys,
// compact survivors to the private segment, count into the LDS histogram.
__device__ __forceinline__ u32 drain(const u64* Qb, u32 n, int lane, int b,
    const float* __restrict__ reg, const float* __restrict__ props,
    u32* hist, u64* seg, u32 wout) {
  for (u32 qb = 0; qb < n; qb += 64) {
    const bool act = (qb + (u32)lane) < n;
    u64 key = act ? Qb[qb + lane] : 0ull;
    bool valid = false;
    u32 sb = 0;
    if (act) {
      sb = (u32)(key >> 32);
      const u32 idx = ~(u32)key;
      const int pn = (int)(idx / CM1);
      const int c = (int)(idx - (u32)pn * CM1) + 1;
      float x1, y1, x2, y2;
      decode_box(b * Np + pn, c, reg, props, x1, y1, x2, y2);
      valid = (__fsub_rn(x2, x1) >= MIN_SZ) && (__fsub_rn(y2, y1) >= MIN_SZ);
    }
    const u64 bal = __ballot(valid);
    if (valid) {
      seg[wout + (u32)__popcll(bal & ((1ull << lane) - 1ull))] = key;
      u32 bk = (sb - BUCK_BASE) >> BUCK_SHIFT;
      if (bk > (u32)(NBUCK - 1)) bk = NBUCK - 1;
      atomicAdd(&hist[bk], 1u);
    }
    wout += (u32)__popcll(bal);
  }
  return wout;
}

// Pass A: direct-register logits loads (no LDS slab), 2 rounds of 16
// proposals per wave. Softmax reduce orders bit-identical to rounds 3..11.
// Emit via per-lane mask + one wave prefix scan (r11-proven) into the LDS
// queue; drain-all after each round -> private per-wave global segment.
__global__ __launch_bounds__(256, 4) void passA_kernel(
    const float* __restrict__ logits, const float* __restrict__ reg,
    const float* __restrict__ props, u64* __restrict__ wseg,
    u32* __restrict__ wcnt, u32* __restrict__ ghist)
{
  __shared__ u64 qbuf[4][QCAP];                        // 10240 B
  __shared__ u32 hist[NBUCK];                          // 8192 B
  const int b = blockIdx.y;
  const int tid = threadIdx.x;
  const int wave = tid >> 6, lane = tid & 63;
  for (int i = tid; i < NBUCK; i += 256) hist[i] = 0;
  __syncthreads();

  const int wslot = (blockIdx.x << 2) + wave;
  u64* Q = qbuf[wave];
  u64* seg = wseg + (size_t)(b * WPI + wslot) * QCAP;
  u32 wout = 0;
  const int p = lane >> 2, qd = lane & 3;
  const int cnt_k = (qd == 3) ? 18 : 21;
  #pragma unroll
  for (int r = 0; r < 2; ++r) {
    const int n0 = wslot * CHUNK + r * 16;
    if (n0 >= Np) break;
    const int n_ = n0 + p;
    const float* lrow = logits + ((size_t)b * Np + n_) * Cc + qd * 21;
    float ev[21];
    #pragma unroll
    for (int k = 0; k < 21; ++k)
      ev[k] = (k < cnt_k) ? lrow[k] : -3.4e38f;
    float m = ev[0];
    #pragma unroll
    for (int k = 1; k < 21; ++k) m = fmaxf(m, ev[k]);
    m = fmaxf(m, __shfl_xor(m, 1, 64));
    m = fmaxf(m, __shfl_xor(m, 2, 64));
    float s = 0.f;
    #pragma unroll
    for (int k = 0; k < 21; ++k) {
      ev[k] = (k < cnt_k) ? expf(ev[k] - m) : 0.f;
      s += ev[k];
    }
    s += __shfl_xor(s, 1, 64);
    s += __shfl_xor(s, 2, 64);
    const float thr = SCORE_TH * s;
    // per-lane emit mask -> one wave prefix scan -> compacted queue writes
    u32 emask = 0;
    #pragma unroll
    for (int k = 0; k < 21; ++k) {
      const int c = qd * 21 + k;
      if (c > 0 && ev[k] > thr) emask |= (1u << k);
    }
    const u32 mycnt = __popc(emask);
    u32 inc = mycnt;
    #pragma unroll
    for (int o = 1; o < 64; o <<= 1) {
      const u32 v = (u32)__shfl_up((int)inc, o, 64);
      if (lane >= o) inc += v;
    }
    u32 pos = inc - mycnt;
    const u32 qtot = (u32)__shfl((int)inc, 63, 64);
    u32 em = emask;
    while (em) {
      const int k = (int)__builtin_ctz(em);
      em &= em - 1;
      const int c = qd * 21 + k;
      const u32 sb = __float_as_uint(__fdiv_rn(ev[k], s));
      const u32 idx = (u32)(n_ * CM1 + (c - 1));
      Q[pos++] = ((u64)sb << 32) | (u32)(~idx);
    }
    // drain the whole round (decode + minsize + hist + segment write)
    wout = drain(Q, qtot, lane, b, reg, props, hist, seg, wout);
  }
  if (lane == 0) wcnt[b * WPI + wslot] = wout;
  __syncthreads();
  for (int i = tid; i < NBUCK; i += 256) {
    const u32 v = hist[i];
    if (v) atomicAdd(&ghist[b * NBUCK + i], v);   // fire-and-forget
  }
}

// Per image: T = largest bucket with inclusive suffix >= KSEL (0 if total
// < KSEL); exclusive suffix offsets; total (clamped); also zeroes bfill
// (removing it from the memset prefix).
__global__ void thresh_kernel(const u32* __restrict__ ghist, u32* __restrict__ gT,
                              u32* __restrict__ gTot, u32* __restrict__ boffs,
                              u32* __restrict__ bfill) {
  const int b = blockIdx.x;
  const int lane = threadIdx.x;  // 64 threads
  const u32* h = ghist + b * NBUCK;
  u32* bo = boffs + b * NBUCK;
  const int SEG = NBUCK / 64;
  u32 segsum = 0;
  for (int t = 0; t < SEG; ++t) segsum += h[lane * SEG + t];
  u32 suf = segsum;
  #pragma unroll
  for (int o = 1; o < 64; o <<= 1) {
    const u32 v = (u32)__shfl_down((int)suf, o, 64);
    if (lane + o < 64) suf += v;
  }
  u32 acc = suf - segsum;   // count in buckets strictly above this segment
  int myT = -1; u32 totv = 0;
  for (int t = SEG - 1; t >= 0; --t) {
    const int bk = lane * SEG + t;
    bo[bk] = acc;
    bfill[b * NBUCK + bk] = 0u;
    acc += h[bk];
    if (myT < 0 && acc >= (u32)KSEL) { myT = bk; totv = acc; }
  }
  int Tg = myT;
  #pragma unroll
  for (int o = 32; o; o >>= 1) Tg = max(Tg, __shfl_xor(Tg, o, 64));
  if (Tg < 0) {
    if (lane == 0) { gT[b] = 0u; gTot[b] = (acc < (u32)SELCAP) ? acc : (u32)SELCAP; }
  } else if (myT == Tg) {
    gT[b] = (u32)Tg;
    gTot[b] = (totv < (u32)SELCAP) ? totv : (u32)SELCAP;
  }
}

// Scatter: wave-per-segment. Keys with bucket >= T (~2100/image) placed
// into skeys via per-bucket fill atomics (no holes: minsize was filtered
// before the histogram, so bfill == hist exactly).
__global__ __launch_bounds__(256) void scatter_kernel(
    const u64* __restrict__ wseg, const u32* __restrict__ wcnt,
    const u32* __restrict__ gT, const u32* __restrict__ boffs,
    u32* __restrict__ bfill, u64* __restrict__ skeys)
{
  const int b = blockIdx.y;
  const u32 T = gT[b];
  const int wave = threadIdx.x >> 6, lane = threadIdx.x & 63;
  const u32 sgi = blockIdx.x * 4 + wave;
  if (sgi >= (u32)WPI) return;
  const u32 cnt = wcnt[b * WPI + sgi];
  const u64* seg = wseg + (size_t)(b * WPI + sgi) * QCAP;
  for (u32 i = lane; i < cnt; i += 64) {
    const u64 key = seg[i];
    const u32 sb = (u32)(key >> 32);
    u32 bk = (sb - BUCK_BASE) >> BUCK_SHIFT;
    if (bk > (u32)(NBUCK - 1)) bk = NBUCK - 1;
    if (bk >= T) {
      const u32 pos = boffs[b * NBUCK + bk] + atomicAdd(&bfill[b * NBUCK + bk], 1u);
      if (pos < (u32)SELCAP) skeys[(size_t)b * SELCAP + pos] = key;
    }
  }
}

// Intra-bucket rank sort, wave-per-bucket across the grid (r6/r9-proven,
// ~3 us), src->dst. Completes the exact (score desc, idx asc) order.
__global__ __launch_bounds__(256) void runsort_kernel(
    const u64* __restrict__ skeys, u64* __restrict__ skeys2,
    const u32* __restrict__ gT, const u32* __restrict__ gTot,
    const u32* __restrict__ boffs, const u32* __restrict__ bfill)
{
  const int b = blockIdx.y;
  const int wave = threadIdx.x >> 6, lane = threadIdx.x & 63;
  const u32 bk = blockIdx.x * RS_WPB + wave;
  if (bk >= (u32)NBUCK || bk < gT[b]) return;
  const u32 total = gTot[b];
  const u32 start = boffs[b * NBUCK + bk];
  u32 L = bfill[b * NBUCK + bk];
  if (L == 0 || start >= (u32)KSEL || start >= total) return;
  if (start + L > total) L = total - start;
  const u64* run = skeys + (size_t)b * SELCAP + start;
  u64* dst = skeys2 + (size_t)b * SELCAP + start;
  if (L <= 128u) {
    const u64 k0 = (lane < (int)L) ? run[lane] : 0ull;
    const u64 k1 = (64 + lane < (int)L) ? run[64 + lane] : 0ull;
    u32 r0 = 0, r1 = 0;
    #pragma unroll
    for (int l = 0; l < 64; ++l) {
      const u64 o0 = shfl64(k0, l);
      const u64 o1 = shfl64(k1, l);
      r0 += (o0 > k0) + (o1 > k0);
      r1 += (o0 > k1) + (o1 > k1);
    }
    if (lane < (int)L) dst[r0] = k0;
    if (64 + lane < (int)L) dst[r1] = k1;
  } else {
    for (u32 i = lane; i < L; i += 64) {
      const u64 k = run[i];
      u32 r = 0;
      for (u32 q = 0; q < L; ++q) r += (run[q] > k);
      dst[r] = k;
    }
  }
}

// Tail (r9-proven): load the globally-sorted top-2048, decode offset
// boxes/areas/scores to LDS, greedy NMS with on-the-fly IoU vs kept list
// (early-exit at 100), decode + write outputs. One block per image.
__global__ __launch_bounds__(1024) void tail_kernel(
    const u64* __restrict__ skeys2, const u32* __restrict__ gTot,
    const float* __restrict__ reg, const float* __restrict__ props,
    float* __restrict__ out)
{
  __shared__ u64 keys[KSEL];                                     // 16 KB
  __shared__ float obx1[KSEL], oby1[KSEL], obx2[KSEL], oby2[KSEL];
  __shared__ float oar[KSEL], osc[KSEL];                         // 48 KB
  __shared__ unsigned short keptIdx[NDET];
  __shared__ u32 supflags[64];
  __shared__ u32 sh_kc;
  const int b = blockIdx.x;
  const int tid = threadIdx.x;
  const int wave = tid >> 6, lane = tid & 63;
  const u32 total = gTot[b];
  if (tid == 0) sh_kc = 0;

  for (int i = tid; i < KSEL; i += 1024)
    keys[i] = (i < (int)total) ? skeys2[(size_t)b * SELCAP + i] : 0ull;
  __syncthreads();

  for (int t = tid; t < KSEL; t += 1024) {
    const u64 key = keys[t];
    float x1 = 0, y1 = 0, x2 = 0, y2 = 0, score = 0, lab = 0;
    if (key) {
      const u32 sb = (u32)(key >> 32);
      const u32 idx = ~(u32)key;
      const int n_ = (int)(idx / CM1);
      const int c = (int)(idx % CM1) + 1;
      score = __uint_as_float(sb);
      decode_box(b * Np + n_, c, reg, props, x1, y1, x2, y2);
      lab = (float)c;
    }
    const float offv = __fmul_rn(lab, LBLOFF);
    const float ox1 = __fadd_rn(x1, offv), oy1 = __fadd_rn(y1, offv);
    const float ox2 = __fadd_rn(x2, offv), oy2 = __fadd_rn(y2, offv);
    obx1[t] = ox1; oby1[t] = oy1; obx2[t] = ox2; oby2[t] = oy2;
    oar[t] = __fmul_rn(__fsub_rn(ox2, ox1), __fsub_rn(oy2, oy1));
    osc[t] = score;
  }
  __syncthreads();

  int kc = 0;
  for (int c = 0; c < 32 && kc < NDET; ++c) {
    if (tid < 64) supflags[tid] = 0;
    __syncthreads();
    const int j = (c << 6) + lane;
    const float cx1 = obx1[j], cy1 = oby1[j], cx2 = obx2[j], cy2 = oby2[j], ca = oar[j];
    bool sup = false;
    for (int k = wave; k < kc; k += 16) {
      const int ki = keptIdx[k];
      const float ltx = fmaxf(cx1, obx1[ki]), lty = fmaxf(cy1, oby1[ki]);
      const float rbx = fminf(cx2, obx2[ki]), rby = fminf(cy2, oby2[ki]);
      const float wx = fmaxf(__fsub_rn(rbx, ltx), 0.f);
      const float wy = fmaxf(__fsub_rn(rby, lty), 0.f);
      const float inter = __fmul_rn(wx, wy);
      const float denom = __fadd_rn(__fsub_rn(__fadd_rn(ca, oar[ki]), inter), 1e-9f);
      if (__fdiv_rn(inter, denom) > NMS_TH) sup = true;
    }
    if (sup) supflags[lane] = 1u;   // benign same-value race
    __syncthreads();
    if (wave == 0) {
      u64 rem = __ballot(supflags[lane] != 0u);
      u64 todo = __ballot(osc[j] > 0.f) & ~rem;
      int kcl = kc;
      while (todo && kcl < NDET) {
        const int jb = (int)__builtin_ctzll(todo);
        const int cj = (c << 6) + jb;
        if (lane == 0) keptIdx[kcl] = (unsigned short)cj;
        ++kcl;
        const float kx1 = obx1[cj], ky1 = oby1[cj], kx2 = obx2[cj], ky2 = oby2[cj], ka = oar[cj];
        const float ltx = fmaxf(kx1, cx1), lty = fmaxf(ky1, cy1);
        const float rbx = fminf(kx2, cx2), rby = fminf(ky2, cy2);
        const float wx = fmaxf(__fsub_rn(rbx, ltx), 0.f);
        const float wy = fmaxf(__fsub_rn(rby, lty), 0.f);
        const float inter = __fmul_rn(wx, wy);
        const float denom = __fadd_rn(__fsub_rn(__fadd_rn(ka, ca), inter), 1e-9f);
        const u64 w = __ballot(__fdiv_rn(inter, denom) > NMS_TH);
        rem |= w;
        todo &= ~rem;
        todo &= ~(1ull << jb);
      }
      if (lane == 0) sh_kc = (u32)kcl;
    }
    __syncthreads();
    kc = (int)sh_kc;
  }

  __syncthreads();
  const int kcl = (kc < NDET) ? kc : NDET;
  if (tid < NDET) {
    float bx1 = 0, by1 = 0, bx2 = 0, by2 = 0, sc = 0, lb = -1.f;
    if (tid < kcl) {
      const int i = keptIdx[tid];
      const u64 key = keys[i];
      const u32 idx = ~(u32)key;
      const int n_ = (int)(idx / CM1);
      const int cc = (int)(idx % CM1) + 1;
      decode_box(b * Np + n_, cc, reg, props, bx1, by1, bx2, by2);
      sc = osc[i];
      lb = (float)cc;
    }
    float* ob = out + (size_t)b * NDET * 4;
    ob[tid * 4 + 0] = bx1; ob[tid * 4 + 1] = by1;
    ob[tid * 4 + 2] = bx2; ob[tid * 4 + 3] = by2;
    out[Bn * NDET * 4 + b * NDET + tid] = sc;
    out[Bn * NDET * 4 + Bn * NDET + b * NDET + tid] = lb;
  }
}

extern "C" void kernel_launch(void* const* d_in, const int* in_sizes, int n_in,
                              void* d_out, int out_size, void* d_ws, size_t ws_size,
                              hipStream_t stream) {
  const float* logits = (const float*)d_in[0];
  const float* reg    = (const float*)d_in[1];
  const float* props  = (const float*)d_in[2];
  float* out = (float*)d_out;
  char* ws = (char*)d_ws;

  // Layout: [header | ghist]  <- memset 0 each call (16 KB)
  //         [bfill (zeroed by thresh) | boffs | skeys | skeys2 | wcnt | wseg]
  u32* gT   = (u32*)ws;                        // 2 u32
  u32* gTot = (u32*)(ws + 16);                 // 2 u32
  size_t off = 64;
  u32* ghist  = (u32*)(ws + off); off += (size_t)Bn * NBUCK * 4;   // 16 KB
  const size_t memset_bytes = off;
  u32* bfill  = (u32*)(ws + off); off += (size_t)Bn * NBUCK * 4;   // 16 KB
  u32* boffs  = (u32*)(ws + off); off += (size_t)Bn * NBUCK * 4;   // 16 KB
  u64* skeys  = (u64*)(ws + off); off += (size_t)Bn * SELCAP * 8;  // 64 KB
  u64* skeys2 = (u64*)(ws + off); off += (size_t)Bn * SELCAP * 8;  // 64 KB
  u32* wcnt   = (u32*)(ws + off); off += (size_t)Bn * WPI * 4;     // 13 KB
  off = (off + 255) & ~(size_t)255;
  u64* wseg   = (u64*)(ws + off); off += (size_t)Bn * WPI * QCAP * 8;  // 8 MB
  (void)ws_size;

  hipMemsetAsync(d_ws, 0, memset_bytes, stream);
  passA_kernel<<<dim3(BLKX, Bn), 256, 0, stream>>>(logits, reg, props, wseg, wcnt, ghist);
  thresh_kernel<<<dim3(Bn), 64, 0, stream>>>(ghist, gT, gTot, boffs, bfill);
  scatter_kernel<<<dim3((WPI + 3) / 4, Bn), 256, 0, stream>>>(wseg, wcnt, gT, boffs, bfill, skeys);
  runsort_kernel<<<dim3(NBUCK / RS_WPB, Bn), 256, 0, stream>>>(skeys, skeys2, gT, gTot, boffs, bfill);
  tail_kernel<<<dim3(Bn), 1024, 0, stream>>>(skeys2, gTot, reg, props, out);
}